// Round 16
// baseline (71.896 us; speedup 1.0000x reference)
//
#include <hip/hip_runtime.h>
#include <math.h>

#define BB 8
#define NN 256
#define DD 128
#define HH 256
#define LN_EPS 1e-5f

// gelu2(x) = 2*gelu(x), branch-free A-S 7.1.26 erf. Also the VALU-wave hot path.
__device__ __forceinline__ float gelu2(float x) {
    const float x2 = x * x;
    const float q  = fmaf(fabsf(x), 0.23164429f, 1.0f);
    const float tt = __builtin_amdgcn_rcpf(q);
    const float e  = __builtin_amdgcn_exp2f(x2 * -0.72134752f);
    float p = fmaf(tt, 1.061405429f, -1.453152027f);
    p = fmaf(tt, p, 1.421413741f);
    p = fmaf(tt, p, -0.284496736f);
    p = fmaf(tt, p, 0.254829592f);
    const float erf_abs = fmaf(-p * tt, e, 1.0f);
    return fmaf(fabsf(x), erf_abs, x);
}

// Kernel 1: hi = slots @ W_m1[:D] + b_m1 ; hj = slots @ W_m1[D:]
__global__ __launch_bounds__(512, 8) void k_proj_m1(
    const float* __restrict__ slots, const float* __restrict__ W_m1,
    const float* __restrict__ b_m1, float* __restrict__ hi, float* __restrict__ hj)
{
    __shared__ __align__(16) float s[DD][4];
    const int t = threadIdx.x;
    const int h = t & (HH - 1);
    const int half = t >> 8;
    const int row0 = blockIdx.x * 4;
    {
        const int r = t & 3, d = t >> 2;
        s[d][r] = slots[(row0 + r) * DD + d];
    }
    __syncthreads();
    const float init = half ? 0.0f : b_m1[h];
    float a0 = init, a1 = init, a2 = init, a3 = init;
    const float* __restrict__ W = W_m1 + half * DD * HH + h;
    #pragma unroll 4
    for (int d = 0; d < DD; ++d) {
        const float w = W[d * HH];
        const float4 sv = *(const float4*)&s[d][0];
        a0 = fmaf(sv.x, w, a0);
        a1 = fmaf(sv.y, w, a1);
        a2 = fmaf(sv.z, w, a2);
        a3 = fmaf(sv.w, w, a3);
    }
    float* __restrict__ dst = half ? hj : hi;
    dst[(row0 + 0) * HH + h] = a0;
    dst[(row0 + 1) * HH + h] = a1;
    dst[(row0 + 2) * HH + h] = a2;
    dst[(row0 + 3) * HH + h] = a3;
}

// Kernel 2 (hot): g[b,i,h] = sum_j A[b,i,j]*gelu(hi[b,i,h]+hj[b,j,h]); asum = sum_j A
// 2 rows/block, 1024 blocks x 256 threads (4 waves = j-quarters of 64).
// PIPE-SPLIT gelu: waves jq 0,1 use the 128-seg fp16 PWL table (DS pipe, at its
// gather-throughput limit); waves jq 2,3 compute exact A-S erf gelu2 (VALU pipe).
// Balances the two pipes (~23us pole each) instead of saturating DS alone.
__global__ __launch_bounds__(256, 4) void k_msg_agg(
    const float* __restrict__ adj, const float* __restrict__ hi,
    const float* __restrict__ hj, float* __restrict__ g, float* __restrict__ asum)
{
    __shared__ __align__(16) unsigned tabu[128 * 32]; // 16KB fp16-pair PWL table
    __shared__ __align__(16) float At2[NN][2];        // 2KB A transposed (2 rows)
    __shared__ __align__(16) float pg[3][2][HH];      // 6KB partials from jq=1..3
    const int t = threadIdx.x;
    const int row0 = blockIdx.x * 2;
    const int b = row0 >> 8;
    const int jq = t >> 6;                       // wave id = j-quarter
    const int h0 = (t & 63) * 4;
    const int cidx = t & 31;                     // table copy = lane&31

    if (t < 128) {   // Build table: quantize slope first, anchor at midpoint.
        const float x0 = (float)t * 0.08f - 5.12f;
        const float x1 = x0 + 0.08f;
        const float xm = x0 + 0.04f;
        const float g0 = 0.5f * gelu2(x0);
        const float g1 = 0.5f * gelu2(x1);
        const float gm = 0.5f * gelu2(xm);
        const _Float16 hs = (_Float16)((g1 - g0) * 12.5f);
        const float slq = (float)hs;
        const _Float16 hc = (_Float16)(fmaf(-slq, xm, gm));
        const unsigned word = (unsigned)*(const unsigned short*)&hs
                            | ((unsigned)*(const unsigned short*)&hc << 16);
        #pragma unroll
        for (int c = 0; c < 32; ++c) tabu[t * 32 + c] = word;
    }
    {   // stage A transposed: 512 entries, 2 per thread
        #pragma unroll
        for (int k = t; k < 2 * NN; k += 256) {
            const int j = k >> 1, r = k & 1;
            At2[j][r] = adj[(size_t)(row0 + r) * NN + j];
        }
    }
    if (t < 128) {                               // waves 0-1: adjacency row sums
        const int r = t >> 6, l = t & 63;
        const float* __restrict__ ar = adj + (size_t)(row0 + r) * NN;
        float s1 = ar[l] + ar[l + 64] + ar[l + 128] + ar[l + 192];
        #pragma unroll
        for (int o = 32; o > 0; o >>= 1) s1 += __shfl_down(s1, o, 64);
        if (l == 0) asum[row0 + r] = s1;
    }
    __syncthreads();

    const int jbase = __builtin_amdgcn_readfirstlane(jq * 64);
    const float4 hv0 = *(const float4*)(hi + (size_t)(row0 + 0) * HH + h0);
    const float4 hv1 = *(const float4*)(hi + (size_t)(row0 + 1) * HH + h0);
    const float* __restrict__ hjp = hj + ((size_t)b * NN + jbase) * HH + h0;

    float acc[16];
    #pragma unroll
    for (int k = 0; k < 16; ++k) acc[k] = 0.0f;

    float4 c0 = *(const float4*)(hjp);
    float4 c1 = *(const float4*)(hjp + HH);
    #pragma unroll 1
    for (int jj = 0; jj < 64; jj += 2) {
        // unconditional prefetch (last iter reads slack; values unused)
        const float4 n0 = *(const float4*)(hjp + (size_t)(jj + 2) * HH);
        const float4 n1 = *(const float4*)(hjp + (size_t)(jj + 3) * HH);
        // A for GLOBAL j = jbase+jj, jbase+jj+1 x rows 0,1 (uniform b128)
        const float4 Aj = *(const float4*)&At2[jbase + jj][0];
        // phase 1: all 16 xs
        float xs[16];
        xs[0]  = hv0.x + c0.x; xs[1]  = hv0.y + c0.y;
        xs[2]  = hv0.z + c0.z; xs[3]  = hv0.w + c0.w;
        xs[4]  = hv1.x + c0.x; xs[5]  = hv1.y + c0.y;
        xs[6]  = hv1.z + c0.z; xs[7]  = hv1.w + c0.w;
        xs[8]  = hv0.x + c1.x; xs[9]  = hv0.y + c1.y;
        xs[10] = hv0.z + c1.z; xs[11] = hv0.w + c1.w;
        xs[12] = hv1.x + c1.x; xs[13] = hv1.y + c1.y;
        xs[14] = hv1.z + c1.z; xs[15] = hv1.w + c1.w;
        if (jq < 2) {
            // ---- table path (DS pipe): gelu via 1 ds_read_b32 per value ----
            int ad[16];
            #pragma unroll
            for (int k = 0; k < 16; ++k) {
                unsigned u = (unsigned)fmaf(xs[k], 12.5f, 64.0f);
                u = u < 127u ? u : 127u;
                ad[k] = (int)(u * 32u) + cidx;
            }
            unsigned se[16];
            #pragma unroll
            for (int k = 0; k < 16; ++k) se[k] = tabu[ad[k]];
            #pragma unroll
            for (int k = 0; k < 16; ++k) {
                float r;
                asm("v_fma_mix_f32 %0, %1, %2, %1 op_sel:[0,0,1] op_sel_hi:[1,0,1]"
                    : "=v"(r) : "v"(se[k]), "v"(xs[k]));
                const float A = (k < 4) ? Aj.x : (k < 8) ? Aj.y : (k < 12) ? Aj.z : Aj.w;
                acc[k] = fmaf(A, r, acc[k]);           // acc in units of gelu
            }
        } else {
            // ---- erf path (VALU pipe): exact branch-free gelu2 ----
            #pragma unroll
            for (int k = 0; k < 16; ++k) {
                const float A = (k < 4) ? Aj.x : (k < 8) ? Aj.y : (k < 12) ? Aj.z : Aj.w;
                acc[k] = fmaf(A, gelu2(xs[k]), acc[k]); // acc in units of 2*gelu
            }
        }
        c0 = n0; c1 = n1;
    }
    if (jq >= 2) {                                // normalize erf-wave partials
        #pragma unroll
        for (int k = 0; k < 16; ++k) acc[k] *= 0.5f;
    }

    const float4 t0 = make_float4(acc[0] + acc[8],  acc[1] + acc[9],
                                  acc[2] + acc[10], acc[3] + acc[11]);
    const float4 t1 = make_float4(acc[4] + acc[12], acc[5] + acc[13],
                                  acc[6] + acc[14], acc[7] + acc[15]);
    if (jq) {
        *(float4*)&pg[jq - 1][0][h0] = t0;
        *(float4*)&pg[jq - 1][1][h0] = t1;
    }
    __syncthreads();
    if (!jq) {
        const float4 p00 = *(const float4*)&pg[0][0][h0];
        const float4 p10 = *(const float4*)&pg[1][0][h0];
        const float4 p20 = *(const float4*)&pg[2][0][h0];
        const float4 p01 = *(const float4*)&pg[0][1][h0];
        const float4 p11 = *(const float4*)&pg[1][1][h0];
        const float4 p21 = *(const float4*)&pg[2][1][h0];
        *(float4*)(g + (size_t)(row0 + 0) * HH + h0) =
            make_float4(t0.x + p00.x + p10.x + p20.x,
                        t0.y + p00.y + p10.y + p20.y,
                        t0.z + p00.z + p10.z + p20.z,
                        t0.w + p00.w + p10.w + p20.w);
        *(float4*)(g + (size_t)(row0 + 1) * HH + h0) =
            make_float4(t1.x + p01.x + p11.x + p21.x,
                        t1.y + p01.y + p11.y + p21.y,
                        t1.z + p01.z + p11.z + p21.z,
                        t1.w + p01.w + p11.w + p21.w);
    }
}

// Kernel 3: ag = g@W_m2 + asum*b_m2 ; u = sl@W_u1[:D] + ag@W_u1[D:] + b_u1
//           u = gelu(LN(u)) ; out = slots + u@W_u2 + b_u2
// 4 rows/block, 512 threads, 512 blocks.
__global__ __launch_bounds__(512, 4) void k_update(
    const float* __restrict__ slots, const float* __restrict__ g,
    const float* __restrict__ asum,
    const float* __restrict__ W_m2, const float* __restrict__ b_m2,
    const float* __restrict__ W_u1, const float* __restrict__ b_u1,
    const float* __restrict__ ln_g, const float* __restrict__ ln_b,
    const float* __restrict__ W_u2, const float* __restrict__ b_u2,
    float* __restrict__ out)
{
    __shared__ __align__(16) float gl[HH][4];   // 4KB  gl[h][r]
    __shared__ __align__(16) float sl[DD][4];   // 2KB
    __shared__ __align__(16) float ag[DD][4];   // 2KB
    __shared__ float ul[HH][5];                 // 5KB stride 5 (conflict-free writes)
    __shared__ float4 red[2][4];
    __shared__ float arena[2560];               // 10KB: pA[4][128][5] / pB[2][256][5]
    const int t = threadIdx.x;
    const int row0 = blockIdx.x * 4;

    {   // stage gl: 1024 entries, coalesced in hh
        int k = t;
        #pragma unroll
        for (int it = 0; it < 2; ++it, k += 512) {
            const int hh = k & 255, r = k >> 8;
            gl[hh][r] = g[(row0 + r) * HH + hh];
        }
        const int d = t & 127, r2 = t >> 7;     // 512 = 4*128 exactly
        sl[d][r2] = slots[(row0 + r2) * DD + d];
    }
    __syncthreads();

    const int d_ = t & (DD - 1);
    const int hc = t >> 7;                      // 0..3
    // Phase A: partial ag over 64-hh chunk
    {
        float pa[4] = {0, 0, 0, 0};
        const float* __restrict__ W = W_m2 + d_;
        const int hh0 = hc * 64;
        #pragma unroll 4
        for (int hh = hh0; hh < hh0 + 64; ++hh) {
            const float w = W[hh * DD];
            const float4 g0 = *(const float4*)&gl[hh][0];   // broadcast
            pa[0] = fmaf(g0.x, w, pa[0]); pa[1] = fmaf(g0.y, w, pa[1]);
            pa[2] = fmaf(g0.z, w, pa[2]); pa[3] = fmaf(g0.w, w, pa[3]);
        }
        float* pw = arena + hc * 640 + d_ * 5;
        #pragma unroll
        for (int r = 0; r < 4; ++r) pw[r] = pa[r];
    }
    __syncthreads();
    {   // combine A: (d = t&127, r = t>>7)
        const int r = t >> 7;
        float acc = asum[row0 + r] * b_m2[d_];
        #pragma unroll
        for (int c = 0; c < 4; ++c) acc += arena[c * 640 + d_ * 5 + r];
        ag[d_][r] = acc;
    }
    __syncthreads();

    const int h = t & (HH - 1);
    const int dc = t >> 8;                      // 0..1
    // Phase B: partial u over 64-d chunk
    {
        float pu[4] = {0, 0, 0, 0};
        const float* __restrict__ W1 = W_u1 + h;
        const float* __restrict__ W2 = W_u1 + DD * HH + h;
        const int d0 = dc * 64;
        #pragma unroll 2
        for (int d = d0; d < d0 + 64; ++d) {
            const float w1 = W1[d * HH];
            const float w2 = W2[d * HH];
            const float4 s0 = *(const float4*)&sl[d][0];
            const float4 a0 = *(const float4*)&ag[d][0];
            pu[0] = fmaf(s0.x, w1, pu[0]); pu[0] = fmaf(a0.x, w2, pu[0]);
            pu[1] = fmaf(s0.y, w1, pu[1]); pu[1] = fmaf(a0.y, w2, pu[1]);
            pu[2] = fmaf(s0.z, w1, pu[2]); pu[2] = fmaf(a0.z, w2, pu[2]);
            pu[3] = fmaf(s0.w, w1, pu[3]); pu[3] = fmaf(a0.w, w2, pu[3]);
        }
        float* pw = arena + dc * 1280 + h * 5;
        #pragma unroll
        for (int r = 0; r < 4; ++r) pw[r] = pu[r];
    }
    __syncthreads();

    // combine B + LayerNorm + gelu. (h = t&255, rg = t>>8) rows {2rg, 2rg+1}
    const int rg = t >> 8;
    {
        const float bu = b_u1[h];
        float u0 = bu + arena[h * 5 + 2 * rg]     + arena[1280 + h * 5 + 2 * rg];
        float u1 = bu + arena[h * 5 + 2 * rg + 1] + arena[1280 + h * 5 + 2 * rg + 1];
        float s1a = u0, s2a = u0 * u0, s1b = u1, s2b = u1 * u1;
        #pragma unroll
        for (int o = 32; o > 0; o >>= 1) {
            s1a += __shfl_xor(s1a, o, 64);
            s2a += __shfl_xor(s2a, o, 64);
            s1b += __shfl_xor(s1b, o, 64);
            s2b += __shfl_xor(s2b, o, 64);
        }
        if ((t & 63) == 0) red[rg][(t >> 6) & 3] = make_float4(s1a, s2a, s1b, s2b);
        __syncthreads();
        const float4 r0 = red[rg][0], r1 = red[rg][1], r2 = red[rg][2], r3 = red[rg][3];
        const float lgv = ln_g[h], lbv = ln_b[h];
        const float t1a = r0.x + r1.x + r2.x + r3.x;
        const float t2a = r0.y + r1.y + r2.y + r3.y;
        const float t1b = r0.z + r1.z + r2.z + r3.z;
        const float t2b = r0.w + r1.w + r2.w + r3.w;
        const float mu0 = t1a * (1.0f / HH);
        const float var0 = t2a * (1.0f / HH) - mu0 * mu0;
        const float mu1 = t1b * (1.0f / HH);
        const float var1 = t2b * (1.0f / HH) - mu1 * mu1;
        ul[h][2 * rg]     = 0.5f * gelu2((u0 - mu0) * rsqrtf(var0 + LN_EPS) * lgv + lbv);
        ul[h][2 * rg + 1] = 0.5f * gelu2((u1 - mu1) * rsqrtf(var1 + LN_EPS) * lgv + lbv);
    }
    __syncthreads();

    // Phase D: partial out over 64-hh chunk (ul scalar broadcasts)
    {
        float pd[4] = {0, 0, 0, 0};
        const float* __restrict__ W = W_u2 + d_;
        const int hh0 = hc * 64;
        #pragma unroll 4
        for (int hh = hh0; hh < hh0 + 64; ++hh) {
            const float w = W[hh * DD];
            pd[0] = fmaf(ul[hh][0], w, pd[0]);
            pd[1] = fmaf(ul[hh][1], w, pd[1]);
            pd[2] = fmaf(ul[hh][2], w, pd[2]);
            pd[3] = fmaf(ul[hh][3], w, pd[3]);
        }
        float* pw = arena + hc * 640 + d_ * 5;
        #pragma unroll
        for (int r = 0; r < 4; ++r) pw[r] = pd[r];
    }
    __syncthreads();
    {   // combine D
        const int r = t >> 7;
        float acc = b_u2[d_];
        #pragma unroll
        for (int c = 0; c < 4; ++c) acc += arena[c * 640 + d_ * 5 + r];
        out[(row0 + r) * DD + d_] = sl[d_][r] + acc;
    }
}

extern "C" void kernel_launch(void* const* d_in, const int* in_sizes, int n_in,
                              void* d_out, int out_size, void* d_ws, size_t ws_size,
                              hipStream_t stream) {
    const float* slots = (const float*)d_in[0];
    const float* adj   = (const float*)d_in[1];
    const float* W_m1  = (const float*)d_in[2];
    const float* b_m1  = (const float*)d_in[3];
    const float* W_m2  = (const float*)d_in[4];
    const float* b_m2  = (const float*)d_in[5];
    const float* W_u1  = (const float*)d_in[6];
    const float* b_u1  = (const float*)d_in[7];
    const float* ln_g  = (const float*)d_in[8];
    const float* ln_b  = (const float*)d_in[9];
    const float* W_u2  = (const float*)d_in[10];
    const float* b_u2  = (const float*)d_in[11];
    float* out = (float*)d_out;
    float* ws  = (float*)d_ws;

    const int rows = BB * NN;            // 2048
    float* hi   = ws;
    float* hj   = hi + (size_t)rows * HH;
    float* g    = hj + (size_t)rows * HH;
    float* asum = g  + (size_t)rows * HH;

    hipLaunchKernelGGL(k_proj_m1, dim3(rows / 4), dim3(512), 0, stream,
                       slots, W_m1, b_m1, hi, hj);
    hipLaunchKernelGGL(k_msg_agg, dim3(rows / 2), dim3(256), 0, stream,
                       adj, hi, hj, g, asum);
    hipLaunchKernelGGL(k_update, dim3(rows / 4), dim3(512), 0, stream,
                       slots, g, asum, W_m2, b_m2, W_u1, b_u1,
                       ln_g, ln_b, W_u2, b_u2, out);
}

// Round 17
// 59.552 us; speedup vs baseline: 1.2073x; 1.2073x over previous
//
#include <hip/hip_runtime.h>
#include <math.h>

#define BB 8
#define NN 256
#define DD 128
#define HH 256
#define LN_EPS 1e-5f

// gelu2(x) = 2*gelu(x), branch-free A-S 7.1.26 erf. Table build + epilogue only.
__device__ __forceinline__ float gelu2(float x) {
    const float x2 = x * x;
    const float q  = fmaf(fabsf(x), 0.23164429f, 1.0f);
    const float tt = __builtin_amdgcn_rcpf(q);
    const float e  = __builtin_amdgcn_exp2f(x2 * -0.72134752f);
    float p = fmaf(tt, 1.061405429f, -1.453152027f);
    p = fmaf(tt, p, 1.421413741f);
    p = fmaf(tt, p, -0.284496736f);
    p = fmaf(tt, p, 0.254829592f);
    const float erf_abs = fmaf(-p * tt, e, 1.0f);
    return fmaf(fabsf(x), erf_abs, x);
}

// Kernel 1: hi = slots @ W_m1[:D] + b_m1 ; hj = slots @ W_m1[D:]
__global__ __launch_bounds__(512, 8) void k_proj_m1(
    const float* __restrict__ slots, const float* __restrict__ W_m1,
    const float* __restrict__ b_m1, float* __restrict__ hi, float* __restrict__ hj)
{
    __shared__ __align__(16) float s[DD][4];
    const int t = threadIdx.x;
    const int h = t & (HH - 1);
    const int half = t >> 8;
    const int row0 = blockIdx.x * 4;
    {
        const int r = t & 3, d = t >> 2;
        s[d][r] = slots[(row0 + r) * DD + d];
    }
    __syncthreads();
    const float init = half ? 0.0f : b_m1[h];
    float a0 = init, a1 = init, a2 = init, a3 = init;
    const float* __restrict__ W = W_m1 + half * DD * HH + h;
    #pragma unroll 4
    for (int d = 0; d < DD; ++d) {
        const float w = W[d * HH];
        const float4 sv = *(const float4*)&s[d][0];
        a0 = fmaf(sv.x, w, a0);
        a1 = fmaf(sv.y, w, a1);
        a2 = fmaf(sv.z, w, a2);
        a3 = fmaf(sv.w, w, a3);
    }
    float* __restrict__ dst = half ? hj : hi;
    dst[(row0 + 0) * HH + h] = a0;
    dst[(row0 + 1) * HH + h] = a1;
    dst[(row0 + 2) * HH + h] = a2;
    dst[(row0 + 3) * HH + h] = a3;
}

// Kernel 2 (hot): g[b,i,h] = sum_j A[b,i,j]*gelu(hi[b,i,h]+hj[b,j,h]); asum = sum_j A
// 2 rows/block, 1024 blocks x 256 threads (4 waves = j-quarters of 64).
// PWL gelu: 128-seg [-5.12,5.12) fp16 (slope,icpt) packed u32, quantized-slope
// MIDPOINT-anchored. 32 conflict-free copies (16KB, bank == lane&31).
// A staged transposed in LDS, indexed by GLOBAL j = jbase+jj:
// one uniform ds_read_b128 per 2-j iter (pure-DS in-order lgkm stream).
__global__ __launch_bounds__(256, 4) void k_msg_agg(
    const float* __restrict__ adj, const float* __restrict__ hi,
    const float* __restrict__ hj, float* __restrict__ g, float* __restrict__ asum)
{
    __shared__ __align__(16) unsigned tabu[128 * 32]; // 16KB fp16-pair PWL table
    __shared__ __align__(16) float At2[NN][2];        // 2KB A transposed (2 rows)
    __shared__ __align__(16) float pg[3][2][HH];      // 6KB partials from jq=1..3
    const int t = threadIdx.x;
    const int row0 = blockIdx.x * 2;
    const int b = row0 >> 8;
    const int jq = t >> 6;                       // wave id = j-quarter
    const int h0 = (t & 63) * 4;
    const int cidx = t & 31;                     // table copy = lane&31

    if (t < 128) {   // Build table: quantize slope first, anchor at midpoint.
        const float x0 = (float)t * 0.08f - 5.12f;
        const float x1 = x0 + 0.08f;
        const float xm = x0 + 0.04f;
        const float g0 = 0.5f * gelu2(x0);
        const float g1 = 0.5f * gelu2(x1);
        const float gm = 0.5f * gelu2(xm);
        const _Float16 hs = (_Float16)((g1 - g0) * 12.5f);
        const float slq = (float)hs;
        const _Float16 hc = (_Float16)(fmaf(-slq, xm, gm));
        const unsigned word = (unsigned)*(const unsigned short*)&hs
                            | ((unsigned)*(const unsigned short*)&hc << 16);
        #pragma unroll
        for (int c = 0; c < 32; ++c) tabu[t * 32 + c] = word;
    }
    {   // stage A transposed: 512 entries, 2 per thread
        #pragma unroll
        for (int k = t; k < 2 * NN; k += 256) {
            const int j = k >> 1, r = k & 1;
            At2[j][r] = adj[(size_t)(row0 + r) * NN + j];
        }
    }
    if (t < 128) {                               // waves 0-1: adjacency row sums
        const int r = t >> 6, l = t & 63;
        const float* __restrict__ ar = adj + (size_t)(row0 + r) * NN;
        float s1 = ar[l] + ar[l + 64] + ar[l + 128] + ar[l + 192];
        #pragma unroll
        for (int o = 32; o > 0; o >>= 1) s1 += __shfl_down(s1, o, 64);
        if (l == 0) asum[row0 + r] = s1;
    }
    __syncthreads();

    const int jbase = __builtin_amdgcn_readfirstlane(jq * 64);
    const float4 hv0 = *(const float4*)(hi + (size_t)(row0 + 0) * HH + h0);
    const float4 hv1 = *(const float4*)(hi + (size_t)(row0 + 1) * HH + h0);
    const float* __restrict__ hjp = hj + ((size_t)b * NN + jbase) * HH + h0;

    float acc[16];
    #pragma unroll
    for (int k = 0; k < 16; ++k) acc[k] = 0.0f;

    float4 c0 = *(const float4*)(hjp);
    float4 c1 = *(const float4*)(hjp + HH);
    #pragma unroll 1
    for (int jj = 0; jj < 64; jj += 2) {
        // unconditional prefetch (last iter reads slack; values unused)
        const float4 n0 = *(const float4*)(hjp + (size_t)(jj + 2) * HH);
        const float4 n1 = *(const float4*)(hjp + (size_t)(jj + 3) * HH);
        // A for GLOBAL j = jbase+jj, jbase+jj+1 x rows 0,1 (uniform b128)
        const float4 Aj = *(const float4*)&At2[jbase + jj][0];
        // phase 1: all 16 xs
        float xs[16];
        xs[0]  = hv0.x + c0.x; xs[1]  = hv0.y + c0.y;
        xs[2]  = hv0.z + c0.z; xs[3]  = hv0.w + c0.w;
        xs[4]  = hv1.x + c0.x; xs[5]  = hv1.y + c0.y;
        xs[6]  = hv1.z + c0.z; xs[7]  = hv1.w + c0.w;
        xs[8]  = hv0.x + c1.x; xs[9]  = hv0.y + c1.y;
        xs[10] = hv0.z + c1.z; xs[11] = hv0.w + c1.w;
        xs[12] = hv1.x + c1.x; xs[13] = hv1.y + c1.y;
        xs[14] = hv1.z + c1.z; xs[15] = hv1.w + c1.w;
        // phase 2: all 16 word indices (cvt_u32 saturates negatives to 0)
        int ad[16];
        #pragma unroll
        for (int k = 0; k < 16; ++k) {
            unsigned u = (unsigned)fmaf(xs[k], 12.5f, 64.0f);
            u = u < 127u ? u : 127u;
            ad[k] = (int)(u * 32u) + cidx;
        }
        // phase 3: issue all 16 ds_read_b32 (conflict-free, latency hidden)
        unsigned se[16];
        #pragma unroll
        for (int k = 0; k < 16; ++k) se[k] = tabu[ad[k]];
        // phase 4: r = f16lo(se)*xs + f16hi(se); acc += A*r
        #pragma unroll
        for (int k = 0; k < 16; ++k) {
            float r;
            asm("v_fma_mix_f32 %0, %1, %2, %1 op_sel:[0,0,1] op_sel_hi:[1,0,1]"
                : "=v"(r) : "v"(se[k]), "v"(xs[k]));
            const float A = (k < 4) ? Aj.x : (k < 8) ? Aj.y : (k < 12) ? Aj.z : Aj.w;
            acc[k] = fmaf(A, r, acc[k]);
        }
        c0 = n0; c1 = n1;
    }

    const float4 t0 = make_float4(acc[0] + acc[8],  acc[1] + acc[9],
                                  acc[2] + acc[10], acc[3] + acc[11]);
    const float4 t1 = make_float4(acc[4] + acc[12], acc[5] + acc[13],
                                  acc[6] + acc[14], acc[7] + acc[15]);
    if (jq) {
        *(float4*)&pg[jq - 1][0][h0] = t0;
        *(float4*)&pg[jq - 1][1][h0] = t1;
    }
    __syncthreads();
    if (!jq) {
        const float4 p00 = *(const float4*)&pg[0][0][h0];
        const float4 p10 = *(const float4*)&pg[1][0][h0];
        const float4 p20 = *(const float4*)&pg[2][0][h0];
        const float4 p01 = *(const float4*)&pg[0][1][h0];
        const float4 p11 = *(const float4*)&pg[1][1][h0];
        const float4 p21 = *(const float4*)&pg[2][1][h0];
        *(float4*)(g + (size_t)(row0 + 0) * HH + h0) =
            make_float4(t0.x + p00.x + p10.x + p20.x,
                        t0.y + p00.y + p10.y + p20.y,
                        t0.z + p00.z + p10.z + p20.z,
                        t0.w + p00.w + p10.w + p20.w);
        *(float4*)(g + (size_t)(row0 + 1) * HH + h0) =
            make_float4(t1.x + p01.x + p11.x + p21.x,
                        t1.y + p01.y + p11.y + p21.y,
                        t1.z + p01.z + p11.z + p21.z,
                        t1.w + p01.w + p11.w + p21.w);
    }
}

// Kernel 3: ag = g@W_m2 + asum*b_m2 ; u = sl@W_u1[:D] + ag@W_u1[D:] + b_u1
//           u = gelu(LN(u)) ; out = slots + u@W_u2 + b_u2
// 4 rows/block, 512 threads, 512 blocks.
__global__ __launch_bounds__(512, 4) void k_update(
    const float* __restrict__ slots, const float* __restrict__ g,
    const float* __restrict__ asum,
    const float* __restrict__ W_m2, const float* __restrict__ b_m2,
    const float* __restrict__ W_u1, const float* __restrict__ b_u1,
    const float* __restrict__ ln_g, const float* __restrict__ ln_b,
    const float* __restrict__ W_u2, const float* __restrict__ b_u2,
    float* __restrict__ out)
{
    __shared__ __align__(16) float gl[HH][4];   // 4KB  gl[h][r]
    __shared__ __align__(16) float sl[DD][4];   // 2KB
    __shared__ __align__(16) float ag[DD][4];   // 2KB
    __shared__ float ul[HH][5];                 // 5KB stride 5 (conflict-free writes)
    __shared__ float4 red[2][4];
    __shared__ float arena[2560];               // 10KB: pA[4][128][5] / pB[2][256][5]
    const int t = threadIdx.x;
    const int row0 = blockIdx.x * 4;

    {   // stage gl: 1024 entries, coalesced in hh
        int k = t;
        #pragma unroll
        for (int it = 0; it < 2; ++it, k += 512) {
            const int hh = k & 255, r = k >> 8;
            gl[hh][r] = g[(row0 + r) * HH + hh];
        }
        const int d = t & 127, r2 = t >> 7;     // 512 = 4*128 exactly
        sl[d][r2] = slots[(row0 + r2) * DD + d];
    }
    __syncthreads();

    const int d_ = t & (DD - 1);
    const int hc = t >> 7;                      // 0..3
    // Phase A: partial ag over 64-hh chunk
    {
        float pa[4] = {0, 0, 0, 0};
        const float* __restrict__ W = W_m2 + d_;
        const int hh0 = hc * 64;
        #pragma unroll 4
        for (int hh = hh0; hh < hh0 + 64; ++hh) {
            const float w = W[hh * DD];
            const float4 g0 = *(const float4*)&gl[hh][0];   // broadcast
            pa[0] = fmaf(g0.x, w, pa[0]); pa[1] = fmaf(g0.y, w, pa[1]);
            pa[2] = fmaf(g0.z, w, pa[2]); pa[3] = fmaf(g0.w, w, pa[3]);
        }
        float* pw = arena + hc * 640 + d_ * 5;
        #pragma unroll
        for (int r = 0; r < 4; ++r) pw[r] = pa[r];
    }
    __syncthreads();
    {   // combine A: (d = t&127, r = t>>7)
        const int r = t >> 7;
        float acc = asum[row0 + r] * b_m2[d_];
        #pragma unroll
        for (int c = 0; c < 4; ++c) acc += arena[c * 640 + d_ * 5 + r];
        ag[d_][r] = acc;
    }
    __syncthreads();

    const int h = t & (HH - 1);
    const int dc = t >> 8;                      // 0..1
    // Phase B: partial u over 64-d chunk
    {
        float pu[4] = {0, 0, 0, 0};
        const float* __restrict__ W1 = W_u1 + h;
        const float* __restrict__ W2 = W_u1 + DD * HH + h;
        const int d0 = dc * 64;
        #pragma unroll 2
        for (int d = d0; d < d0 + 64; ++d) {
            const float w1 = W1[d * HH];
            const float w2 = W2[d * HH];
            const float4 s0 = *(const float4*)&sl[d][0];
            const float4 a0 = *(const float4*)&ag[d][0];
            pu[0] = fmaf(s0.x, w1, pu[0]); pu[0] = fmaf(a0.x, w2, pu[0]);
            pu[1] = fmaf(s0.y, w1, pu[1]); pu[1] = fmaf(a0.y, w2, pu[1]);
            pu[2] = fmaf(s0.z, w1, pu[2]); pu[2] = fmaf(a0.z, w2, pu[2]);
            pu[3] = fmaf(s0.w, w1, pu[3]); pu[3] = fmaf(a0.w, w2, pu[3]);
        }
        float* pw = arena + dc * 1280 + h * 5;
        #pragma unroll
        for (int r = 0; r < 4; ++r) pw[r] = pu[r];
    }
    __syncthreads();

    // combine B + LayerNorm + gelu. (h = t&255, rg = t>>8) rows {2rg, 2rg+1}
    const int rg = t >> 8;
    {
        const float bu = b_u1[h];
        float u0 = bu + arena[h * 5 + 2 * rg]     + arena[1280 + h * 5 + 2 * rg];
        float u1 = bu + arena[h * 5 + 2 * rg + 1] + arena[1280 + h * 5 + 2 * rg + 1];
        float s1a = u0, s2a = u0 * u0, s1b = u1, s2b = u1 * u1;
        #pragma unroll
        for (int o = 32; o > 0; o >>= 1) {
            s1a += __shfl_xor(s1a, o, 64);
            s2a += __shfl_xor(s2a, o, 64);
            s1b += __shfl_xor(s1b, o, 64);
            s2b += __shfl_xor(s2b, o, 64);
        }
        if ((t & 63) == 0) red[rg][(t >> 6) & 3] = make_float4(s1a, s2a, s1b, s2b);
        __syncthreads();
        const float4 r0 = red[rg][0], r1 = red[rg][1], r2 = red[rg][2], r3 = red[rg][3];
        const float lgv = ln_g[h], lbv = ln_b[h];
        const float t1a = r0.x + r1.x + r2.x + r3.x;
        const float t2a = r0.y + r1.y + r2.y + r3.y;
        const float t1b = r0.z + r1.z + r2.z + r3.z;
        const float t2b = r0.w + r1.w + r2.w + r3.w;
        const float mu0 = t1a * (1.0f / HH);
        const float var0 = t2a * (1.0f / HH) - mu0 * mu0;
        const float mu1 = t1b * (1.0f / HH);
        const float var1 = t2b * (1.0f / HH) - mu1 * mu1;
        ul[h][2 * rg]     = 0.5f * gelu2((u0 - mu0) * rsqrtf(var0 + LN_EPS) * lgv + lbv);
        ul[h][2 * rg + 1] = 0.5f * gelu2((u1 - mu1) * rsqrtf(var1 + LN_EPS) * lgv + lbv);
    }
    __syncthreads();

    // Phase D: partial out over 64-hh chunk (ul scalar broadcasts)
    {
        float pd[4] = {0, 0, 0, 0};
        const float* __restrict__ W = W_u2 + d_;
        const int hh0 = hc * 64;
        #pragma unroll 4
        for (int hh = hh0; hh < hh0 + 64; ++hh) {
            const float w = W[hh * DD];
            pd[0] = fmaf(ul[hh][0], w, pd[0]);
            pd[1] = fmaf(ul[hh][1], w, pd[1]);
            pd[2] = fmaf(ul[hh][2], w, pd[2]);
            pd[3] = fmaf(ul[hh][3], w, pd[3]);
        }
        float* pw = arena + hc * 640 + d_ * 5;
        #pragma unroll
        for (int r = 0; r < 4; ++r) pw[r] = pd[r];
    }
    __syncthreads();
    {   // combine D
        const int r = t >> 7;
        float acc = b_u2[d_];
        #pragma unroll
        for (int c = 0; c < 4; ++c) acc += arena[c * 640 + d_ * 5 + r];
        out[(row0 + r) * DD + d_] = sl[d_][r] + acc;
    }
}

extern "C" void kernel_launch(void* const* d_in, const int* in_sizes, int n_in,
                              void* d_out, int out_size, void* d_ws, size_t ws_size,
                              hipStream_t stream) {
    const float* slots = (const float*)d_in[0];
    const float* adj   = (const float*)d_in[1];
    const float* W_m1  = (const float*)d_in[2];
    const float* b_m1  = (const float*)d_in[3];
    const float* W_m2  = (const float*)d_in[4];
    const float* b_m2  = (const float*)d_in[5];
    const float* W_u1  = (const float*)d_in[6];
    const float* b_u1  = (const float*)d_in[7];
    const float* ln_g  = (const float*)d_in[8];
    const float* ln_b  = (const float*)d_in[9];
    const float* W_u2  = (const float*)d_in[10];
    const float* b_u2  = (const float*)d_in[11];
    float* out = (float*)d_out;
    float* ws  = (float*)d_ws;

    const int rows = BB * NN;            // 2048
    float* hi   = ws;
    float* hj   = hi + (size_t)rows * HH;
    float* g    = hj + (size_t)rows * HH;
    float* asum = g  + (size_t)rows * HH;

    hipLaunchKernelGGL(k_proj_m1, dim3(rows / 4), dim3(512), 0, stream,
                       slots, W_m1, b_m1, hi, hj);
    hipLaunchKernelGGL(k_msg_agg, dim3(rows / 2), dim3(256), 0, stream,
                       adj, hi, hj, g, asum);
    hipLaunchKernelGGL(k_update, dim3(rows / 4), dim3(512), 0, stream,
                       slots, g, asum, W_m2, b_m2, W_u1, b_u1,
                       ln_g, ln_b, W_u2, b_u2, out);
}